// Round 3
// baseline (769.879 us; speedup 1.0000x reference)
//
#include <hip/hip_runtime.h>
#include <hip/hip_bf16.h>

#define DIMC 192
#define NHEAD 6
#define LTOT 3136
#define HQKV 576
#define MTOT 100352

using bf16x8 = __attribute__((ext_vector_type(8))) short;
using f32x4  = __attribute__((ext_vector_type(4))) float;

static __device__ __forceinline__ unsigned short f2bf(float f) {
  unsigned u = __builtin_bit_cast(unsigned, f);
  u = (u + 0x7FFFu + ((u >> 16) & 1u)) >> 16;
  return (unsigned short)u;
}
static __device__ __forceinline__ float bf2f(unsigned short u) {
  unsigned v = ((unsigned)u) << 16;
  return __builtin_bit_cast(float, v);
}
static __device__ __forceinline__ int iabs(int a) { return a < 0 ? -a : a; }

static __device__ __forceinline__ void gload16(const unsigned short* g, unsigned short* lds) {
  __builtin_amdgcn_global_load_lds(
      (const __attribute__((address_space(1))) void*)g,
      (__attribute__((address_space(3))) void*)lds, 16, 0, 0);
}

// ---- prep: weights -> bf16 W^T [Npad][K] (zero-padded rows); conv w; BN fold ----
__global__ __launch_bounds__(256) void prep_k(
    const float* __restrict__ qkv_w, const float* __restrict__ proj_w,
    const float* __restrict__ fc1_w, const float* __restrict__ fc2_w,
    const float* __restrict__ conv_w,
    const float* __restrict__ bn_g, const float* __restrict__ bn_b,
    const float* __restrict__ bn_m, const float* __restrict__ bn_v,
    unsigned short* __restrict__ qkvT, unsigned short* __restrict__ projT,
    unsigned short* __restrict__ fc1T, unsigned short* __restrict__ fc2T,
    float* __restrict__ convT, float* __restrict__ bnsc, float* __restrict__ bnsh)
{
  int idx = blockIdx.x * 256 + threadIdx.x;
  if (idx < 122880) { int n = idx / 192, k = idx % 192;
    qkvT[idx] = (n < 576) ? f2bf(qkv_w[k * 576 + n]) : 0; return; }
  idx -= 122880;
  if (idx < 49152)  { int n = idx / 192, k = idx % 192;
    projT[idx] = (n < 192) ? f2bf(proj_w[k * 192 + n]) : 0; return; }
  idx -= 49152;
  if (idx < 147456) { int n = idx / 192, k = idx % 192;
    fc1T[idx] = f2bf(fc1_w[k * 768 + n]); return; }
  idx -= 147456;
  if (idx < 196608) { int n = idx / 768, k = idx % 768;
    fc2T[idx] = (n < 192) ? f2bf(fc2_w[k * 192 + n]) : 0; return; }
  idx -= 196608;
  if (idx < 1728)   { int tap = idx / 192, c = idx % 192; convT[idx] = conv_w[c * 9 + tap]; return; }
  idx -= 1728;
  if (idx < 192) {
    float s = bn_g[idx] * rsqrtf(bn_v[idx] + 1e-5f);
    bnsc[idx] = s; bnsh[idx] = bn_b[idx] - bn_m[idx] * s;
  }
}

// ---- LN1 + window partition ----
__global__ __launch_bounds__(256) void ln1_k(
    const float* __restrict__ x, const float* __restrict__ g,
    const float* __restrict__ b, unsigned short* __restrict__ h1)
{
  const int grp = threadIdx.x >> 6, l = threadIdx.x & 63;
  const int m = blockIdx.x * 4 + grp;
  const int w = m / 49, t = m % 49;
  const int bb = w >> 6, win = w & 63;
  const int lpix = ((win >> 3) * 7 + t / 7) * 56 + (win & 7) * 7 + t % 7;
  const float* row = x + ((size_t)bb * LTOT + lpix) * DIMC;
  const bool act = l < 48;
  const int c = l * 4;
  float4 v = make_float4(0.f, 0.f, 0.f, 0.f);
  if (act) v = *(const float4*)(row + c);
  float s = v.x + v.y + v.z + v.w;
  float ss = v.x * v.x + v.y * v.y + v.z * v.z + v.w * v.w;
  #pragma unroll
  for (int off = 1; off < 64; off <<= 1) { s += __shfl_xor(s, off); ss += __shfl_xor(ss, off); }
  float mean = s * (1.f / 192.f);
  float rstd = rsqrtf(ss * (1.f / 192.f) - mean * mean + 1e-5f);
  if (act) {
    float4 gg = *(const float4*)(g + c);
    float4 bv = *(const float4*)(b + c);
    ushort4 o;
    o.x = f2bf((v.x - mean) * rstd * gg.x + bv.x);
    o.y = f2bf((v.y - mean) * rstd * gg.y + bv.y);
    o.z = f2bf((v.z - mean) * rstd * gg.z + bv.z);
    o.w = f2bf((v.w - mean) * rstd * gg.w + bv.w);
    *(ushort4*)(h1 + (size_t)m * DIMC + c) = o;
  }
}

// ---- m97-style bf16 MFMA GEMM: 128x128 tile, BK=64, global_load_lds ----
// EPI 0: out bf16 = acc+bias                 (qkv, stride Nreal)
// EPI 1: out bf16 (win-scatter) = x + acc+b  (proj residual -> x1b)
// EPI 2: out bf16 = gelu(acc+bias)           (fc1, stride 384)
// EPI 3: out f32 += acc          (no bias)   (fc2 nh=1 accumulate)
// EPI 4: out f32 = res(bf16) + acc+bias      (fc2 nh=0)
template<int EPI>
__global__ __launch_bounds__(256) void gemm128_k(
    const unsigned short* __restrict__ Ag, const unsigned short* __restrict__ Bt,
    const float* __restrict__ bias, void* __restrict__ outp,
    const void* __restrict__ res, int Nreal, int K, int ldb)
{
  __shared__ unsigned short As[128 * 64];
  __shared__ unsigned short Bs[128 * 64];
  const int tid = threadIdx.x;
  const int l = tid & 63, w = tid >> 6;
  const int u = l >> 4, ll = l & 15;
  const int wm = w >> 1, wn = w & 1;
  const int m0 = blockIdx.x * 128, n0 = blockIdx.y * 128;
  const int r_off = l >> 3;          // 0..7
  const int c_off = (l & 7) * 8;     // 0..56 (shorts)

  f32x4 acc[4][4] = {};

  for (int k0 = 0; k0 < K; k0 += 64) {
    #pragma unroll
    for (int it = 0; it < 4; ++it) {
      const int row = it * 32 + w * 8 + r_off;
      const int lo = it * 2048 + w * 512 + l * 8;
      gload16(&Ag[(size_t)(m0 + row) * K + k0 + c_off], &As[lo]);
      gload16(&Bt[(size_t)(n0 + row) * ldb + k0 + c_off], &Bs[lo]);
    }
    __syncthreads();
    #pragma unroll
    for (int kk = 0; kk < 2; ++kk) {
      bf16x8 af[4], bfr[4];
      #pragma unroll
      for (int mt = 0; mt < 4; ++mt)
        af[mt] = *(const bf16x8*)&As[(wm * 64 + mt * 16 + ll) * 64 + kk * 32 + u * 8];
      #pragma unroll
      for (int nt = 0; nt < 4; ++nt)
        bfr[nt] = *(const bf16x8*)&Bs[(wn * 64 + nt * 16 + ll) * 64 + kk * 32 + u * 8];
      #pragma unroll
      for (int mt = 0; mt < 4; ++mt)
        #pragma unroll
        for (int nt = 0; nt < 4; ++nt)
          acc[mt][nt] = __builtin_amdgcn_mfma_f32_16x16x32_bf16(af[mt], bfr[nt], acc[mt][nt], 0, 0, 0);
    }
    __syncthreads();
  }

  #pragma unroll
  for (int mt = 0; mt < 4; ++mt)
  #pragma unroll
  for (int r = 0; r < 4; ++r) {
    const int m = m0 + wm * 64 + mt * 16 + u * 4 + r;
    size_t rowbase = 0;
    if (EPI == 1) {
      int wdw = m / 49, t = m % 49;
      int bb = wdw >> 6, win = wdw & 63;
      int lpix = ((win >> 3) * 7 + t / 7) * 56 + (win & 7) * 7 + t % 7;
      rowbase = ((size_t)bb * LTOT + lpix) * DIMC;
    }
    #pragma unroll
    for (int nt = 0; nt < 4; ++nt) {
      const int n = n0 + wn * 64 + nt * 16 + ll;
      if (n >= Nreal) continue;
      float v = acc[mt][nt][r];
      if (EPI != 3) v += bias[n];
      if (EPI == 0) {
        ((unsigned short*)outp)[(size_t)m * Nreal + n] = f2bf(v);
      } else if (EPI == 1) {
        ((unsigned short*)outp)[rowbase + n] = f2bf(((const float*)res)[rowbase + n] + v);
      } else if (EPI == 2) {
        float gl = 0.5f * v * (1.f + erff(v * 0.70710678118654752f));
        ((unsigned short*)outp)[(size_t)m * 384 + n] = f2bf(gl);
      } else if (EPI == 3) {
        size_t o = (size_t)m * Nreal + n;
        ((float*)outp)[o] += v;
      } else {
        size_t o = (size_t)m * Nreal + n;
        ((float*)outp)[o] = bf2f(((const unsigned short*)res)[o]) + v;
      }
    }
  }
}

// ---- windowed attention: one block per window, loops 6 heads ----
__global__ __launch_bounds__(256) void attn_k(
    const unsigned short* __restrict__ qkv, const float* __restrict__ attn_bias,
    unsigned short* __restrict__ o)
{
  __shared__ unsigned short Qs[64 * 40];
  __shared__ unsigned short Ks[64 * 40];
  __shared__ unsigned short Vt[32 * 72];
  __shared__ unsigned short Ps[64 * 72];
  __shared__ float S[64 * 65];
  __shared__ float bias_s[52];
  const int tid = threadIdx.x;
  const int l = tid & 63, wv = tid >> 6;
  const int u = l >> 4, ll = l & 15;
  const int w = blockIdx.x;
  const f32x4 fz = {0.f, 0.f, 0.f, 0.f};

  for (int i = tid; i < 15 * 40; i += 256) {
    Qs[(49 + i / 40) * 40 + i % 40] = 0;
    Ks[(49 + i / 40) * 40 + i % 40] = 0;
  }
  for (int i = tid; i < 32 * 15; i += 256) Vt[(i / 15) * 72 + 49 + i % 15] = 0;

  for (int h = 0; h < NHEAD; ++h) {
    __syncthreads();
    if (tid < 49) bias_s[tid] = attn_bias[h * 49 + tid];
    #pragma unroll
    for (int it = 0; it < 3; ++it) {
      int idx = tid + it * 256;
      if (idx < 588) {
        int row = idx / 12, g = idx % 12;
        int4 v = *(const int4*)&qkv[((size_t)w * 49 + row) * HQKV + h * 96 + g * 8];
        if (g < 4) *(int4*)&Qs[row * 40 + g * 8] = v;
        else if (g < 8) *(int4*)&Ks[row * 40 + (g - 4) * 8] = v;
        else {
          union { int4 v4; unsigned short us[8]; } uu; uu.v4 = v;
          int d0 = (g - 8) * 8;
          #pragma unroll
          for (int e = 0; e < 8; ++e) Vt[(d0 + e) * 72 + row] = uu.us[e];
        }
      }
    }
    __syncthreads();
    bf16x8 qf = *(const bf16x8*)&Qs[(wv * 16 + ll) * 40 + u * 8];
    f32x4 sc[4];
    #pragma unroll
    for (int nj = 0; nj < 4; ++nj) {
      bf16x8 kf = *(const bf16x8*)&Ks[(nj * 16 + ll) * 40 + u * 8];
      sc[nj] = __builtin_amdgcn_mfma_f32_16x16x32_bf16(qf, kf, fz, 0, 0, 0);
    }
    #pragma unroll
    for (int nj = 0; nj < 4; ++nj)
    #pragma unroll
    for (int r = 0; r < 4; ++r) {
      int i = wv * 16 + u * 4 + r;
      int j = nj * 16 + ll;
      float val = -1e30f;
      if (i < 49 && j < 49) {
        int bi = iabs(i / 7 - j / 7) * 7 + iabs(i % 7 - j % 7);
        val = sc[nj][r] * 0.17677669529663689f + bias_s[bi];
      }
      S[i * 65 + j] = val;
    }
    __syncthreads();
    {
      int row = tid >> 2, t4 = tid & 3;
      float mx = -1e30f;
      #pragma unroll
      for (int jj = 0; jj < 16; ++jj) mx = fmaxf(mx, S[row * 65 + t4 + jj * 4]);
      mx = fmaxf(mx, __shfl_xor(mx, 1));
      mx = fmaxf(mx, __shfl_xor(mx, 2));
      float pv[16], sum = 0.f;
      #pragma unroll
      for (int jj = 0; jj < 16; ++jj) {
        float p = __expf(S[row * 65 + t4 + jj * 4] - mx);
        pv[jj] = p; sum += p;
      }
      sum += __shfl_xor(sum, 1);
      sum += __shfl_xor(sum, 2);
      float inv = 1.f / sum;
      #pragma unroll
      for (int jj = 0; jj < 16; ++jj) Ps[row * 72 + t4 + jj * 4] = f2bf(pv[jj] * inv);
    }
    __syncthreads();
    f32x4 oacc[2]; oacc[0] = fz; oacc[1] = fz;
    #pragma unroll
    for (int kk = 0; kk < 2; ++kk) {
      bf16x8 pf = *(const bf16x8*)&Ps[(wv * 16 + ll) * 72 + kk * 32 + u * 8];
      #pragma unroll
      for (int nt = 0; nt < 2; ++nt) {
        bf16x8 vf = *(const bf16x8*)&Vt[(nt * 16 + ll) * 72 + kk * 32 + u * 8];
        oacc[nt] = __builtin_amdgcn_mfma_f32_16x16x32_bf16(pf, vf, oacc[nt], 0, 0, 0);
      }
    }
    #pragma unroll
    for (int nt = 0; nt < 2; ++nt)
    #pragma unroll
    for (int r = 0; r < 4; ++r) {
      int i = wv * 16 + u * 4 + r;
      if (i < 49) {
        int d = nt * 16 + ll;
        o[((size_t)w * 49 + i) * DIMC + h * 32 + d] = f2bf(oacc[nt][r]);
      }
    }
  }
}

// ---- depthwise 3x3 conv (bf16 in) + BN + LN2, XCD-swizzled ----
__global__ __launch_bounds__(256) void conv_k(
    const unsigned short* __restrict__ x1b, const float* __restrict__ wT,
    const float* __restrict__ bnsc, const float* __restrict__ bnsh,
    const float* __restrict__ g2, const float* __restrict__ b2,
    unsigned short* __restrict__ x2, unsigned short* __restrict__ h2)
{
  const int bid = blockIdx.x;
  const int swz = (bid & 7) * 3136 + (bid >> 3);  // 25088 % 8 == 0: bijective
  const int grp = threadIdx.x >> 6, l = threadIdx.x & 63;
  const int gid = swz * 4 + grp;
  const int b = gid / LTOT, p = gid % LTOT;
  const int i = p / 56, j = p % 56;
  const bool act = l < 48;
  const int c = l * 4;
  float4 acc = make_float4(0.f, 0.f, 0.f, 0.f);
  if (act) {
    #pragma unroll
    for (int di = -1; di <= 1; ++di) {
      int ni = i + di;
      if (ni < 0 || ni >= 56) continue;
      #pragma unroll
      for (int dj = -1; dj <= 1; ++dj) {
        int nj = j + dj;
        if (nj < 0 || nj >= 56) continue;
        ushort4 sv = *(const ushort4*)&x1b[((size_t)b * LTOT + ni * 56 + nj) * DIMC + c];
        float4 wv = *(const float4*)&wT[((di + 1) * 3 + (dj + 1)) * DIMC + c];
        acc.x += bf2f(sv.x) * wv.x; acc.y += bf2f(sv.y) * wv.y;
        acc.z += bf2f(sv.z) * wv.z; acc.w += bf2f(sv.w) * wv.w;
      }
    }
    float4 s4 = *(const float4*)&bnsc[c];
    float4 h4 = *(const float4*)&bnsh[c];
    acc.x = acc.x * s4.x + h4.x; acc.y = acc.y * s4.y + h4.y;
    acc.z = acc.z * s4.z + h4.z; acc.w = acc.w * s4.w + h4.w;
    ushort4 xv;
    xv.x = f2bf(acc.x); xv.y = f2bf(acc.y); xv.z = f2bf(acc.z); xv.w = f2bf(acc.w);
    *(ushort4*)&x2[(size_t)gid * DIMC + c] = xv;
  }
  float s = act ? acc.x + acc.y + acc.z + acc.w : 0.f;
  float ss = act ? acc.x * acc.x + acc.y * acc.y + acc.z * acc.z + acc.w * acc.w : 0.f;
  #pragma unroll
  for (int off = 1; off < 64; off <<= 1) { s += __shfl_xor(s, off); ss += __shfl_xor(ss, off); }
  float mean = s * (1.f / 192.f);
  float rstd = rsqrtf(ss * (1.f / 192.f) - mean * mean + 1e-5f);
  if (act) {
    float4 gg = *(const float4*)&g2[c];
    float4 bb = *(const float4*)&b2[c];
    ushort4 ov;
    ov.x = f2bf((acc.x - mean) * rstd * gg.x + bb.x);
    ov.y = f2bf((acc.y - mean) * rstd * gg.y + bb.y);
    ov.z = f2bf((acc.z - mean) * rstd * gg.z + bb.z);
    ov.w = f2bf((acc.w - mean) * rstd * gg.w + bb.w);
    *(ushort4*)&h2[(size_t)gid * DIMC + c] = ov;
  }
}

extern "C" void kernel_launch(void* const* d_in, const int* in_sizes, int n_in,
                              void* d_out, int out_size, void* d_ws, size_t ws_size,
                              hipStream_t stream) {
  const float* x      = (const float*)d_in[0];
  const float* ln1_g  = (const float*)d_in[1];
  const float* ln1_b  = (const float*)d_in[2];
  const float* qkv_w  = (const float*)d_in[3];
  const float* qkv_b  = (const float*)d_in[4];
  const float* proj_w = (const float*)d_in[5];
  const float* proj_b = (const float*)d_in[6];
  const float* attn_b = (const float*)d_in[7];
  const float* conv_w = (const float*)d_in[8];
  const float* bn_g   = (const float*)d_in[9];
  const float* bn_b   = (const float*)d_in[10];
  const float* bn_m   = (const float*)d_in[11];
  const float* bn_v   = (const float*)d_in[12];
  const float* ln2_g  = (const float*)d_in[13];
  const float* ln2_b  = (const float*)d_in[14];
  const float* fc1_w  = (const float*)d_in[15];
  const float* fc1_b  = (const float*)d_in[16];
  const float* fc2_w  = (const float*)d_in[17];
  const float* fc2_b  = (const float*)d_in[18];
  float* out = (float*)d_out;

  // workspace layout, peak 155,189,248 B (same guard as the passing round):
  //  WREG [0,1MiB): qkvT(640x192) projT(256x192) fc1T(768x192) fc2T(256x768) convT bnsc bnsh
  //  A [1MiB, +115,605,504):
  //    phase1: qkv bf16 [M][576]
  //    phase2: x1b @A+0 (38.5MB) ; h2 @A+77,070,336 (38.5MB) ; h3 @A+0 (77MB, after x1b dead)
  //  B [A_end, +38,535,168): h1 -> owin -> x2
  const size_t AOFF = 1048576, BOFF = AOFF + 115605504;
  const size_t NEEDED = BOFF + 38535168;
  if (ws_size < NEEDED) return;

  char* ws = (char*)d_ws;
  unsigned short* qkvT  = (unsigned short*)(ws);
  unsigned short* projT = (unsigned short*)(ws + 245760);
  unsigned short* fc1T  = (unsigned short*)(ws + 344064);
  unsigned short* fc2T  = (unsigned short*)(ws + 638976);
  float*          convT = (float*)(ws + 1032192);
  float*          bnsc  = (float*)(ws + 1039104);
  float*          bnsh  = (float*)(ws + 1039872);

  unsigned short* qkv  = (unsigned short*)(ws + AOFF);
  unsigned short* x1b  = (unsigned short*)(ws + AOFF);
  unsigned short* h3   = (unsigned short*)(ws + AOFF);
  unsigned short* h2   = (unsigned short*)(ws + AOFF + 77070336);
  unsigned short* h1   = (unsigned short*)(ws + BOFF);
  unsigned short* owin = (unsigned short*)(ws + BOFF);
  unsigned short* x2   = (unsigned short*)(ws + BOFF);

  prep_k<<<2024, 256, 0, stream>>>(qkv_w, proj_w, fc1_w, fc2_w, conv_w,
                                   bn_g, bn_b, bn_m, bn_v,
                                   qkvT, projT, fc1T, fc2T, convT, bnsc, bnsh);
  ln1_k<<<25088, 256, 0, stream>>>(x, ln1_g, ln1_b, h1);
  gemm128_k<0><<<dim3(784, 5), 256, 0, stream>>>(h1, qkvT, qkv_b, qkv, nullptr, 576, 192, 192);
  attn_k<<<2048, 256, 0, stream>>>(qkv, attn_b, owin);
  gemm128_k<1><<<dim3(784, 2), 256, 0, stream>>>(owin, projT, proj_b, x1b, x, 192, 192, 192);
  conv_k<<<25088, 256, 0, stream>>>(x1b, convT, bnsc, bnsh, ln2_g, ln2_b, x2, h2);
  // MLP: hidden split 2x384, full-M per pass; h3 reused
  gemm128_k<2><<<dim3(784, 3), 256, 0, stream>>>(h2, fc1T, fc1_b, h3, nullptr, 384, 192, 192);
  gemm128_k<4><<<dim3(784, 2), 256, 0, stream>>>(h3, fc2T, fc2_b, out, x2, 192, 384, 768);
  gemm128_k<2><<<dim3(784, 3), 256, 0, stream>>>(h2, fc1T + 384 * 192, fc1_b + 384, h3, nullptr, 384, 192, 192);
  gemm128_k<3><<<dim3(784, 2), 256, 0, stream>>>(h3, fc2T + 384, nullptr, out, nullptr, 192, 384, 768);
}

// Round 5
// 682.394 us; speedup vs baseline: 1.1282x; 1.1282x over previous
//
#include <hip/hip_runtime.h>
#include <hip/hip_bf16.h>

#define DIMC 192
#define NHEAD 6
#define LTOT 3136
#define HQKV 576
#define MTOT 100352

using bf16x8 = __attribute__((ext_vector_type(8))) short;
using f32x4  = __attribute__((ext_vector_type(4))) float;

static __device__ __forceinline__ unsigned short f2bf(float f) {
  unsigned u = __builtin_bit_cast(unsigned, f);
  u = (u + 0x7FFFu + ((u >> 16) & 1u)) >> 16;
  return (unsigned short)u;
}
static __device__ __forceinline__ float bf2f(unsigned short u) {
  unsigned v = ((unsigned)u) << 16;
  return __builtin_bit_cast(float, v);
}
static __device__ __forceinline__ int iabs(int a) { return a < 0 ? -a : a; }

static __device__ __forceinline__ void gload16(const unsigned short* g, unsigned short* lds) {
  __builtin_amdgcn_global_load_lds(
      (const __attribute__((address_space(1))) void*)g,
      (__attribute__((address_space(3))) void*)lds, 16, 0, 0);
}

// ---- prep: weights -> bf16 W^T [Npad][K]; conv w; BN fold ----
__global__ __launch_bounds__(256) void prep_k(
    const float* __restrict__ qkv_w, const float* __restrict__ proj_w,
    const float* __restrict__ fc1_w, const float* __restrict__ fc2_w,
    const float* __restrict__ conv_w,
    const float* __restrict__ bn_g, const float* __restrict__ bn_b,
    const float* __restrict__ bn_m, const float* __restrict__ bn_v,
    unsigned short* __restrict__ qkvT, unsigned short* __restrict__ projT,
    unsigned short* __restrict__ fc1T, unsigned short* __restrict__ fc2T,
    float* __restrict__ convT, float* __restrict__ bnsc, float* __restrict__ bnsh)
{
  int idx = blockIdx.x * 256 + threadIdx.x;
  if (idx < 122880) { int n = idx / 192, k = idx % 192;
    qkvT[idx] = (n < 576) ? f2bf(qkv_w[k * 576 + n]) : 0; return; }
  idx -= 122880;
  if (idx < 49152)  { int n = idx / 192, k = idx % 192;
    projT[idx] = (n < 192) ? f2bf(proj_w[k * 192 + n]) : 0; return; }
  idx -= 49152;
  if (idx < 147456) { int n = idx / 192, k = idx % 192;
    fc1T[idx] = f2bf(fc1_w[k * 768 + n]); return; }
  idx -= 147456;
  if (idx < 196608) { int n = idx / 768, k = idx % 768;
    fc2T[idx] = (n < 192) ? f2bf(fc2_w[k * 192 + n]) : 0; return; }
  idx -= 196608;
  if (idx < 1728)   { int tap = idx / 192, c = idx % 192; convT[idx] = conv_w[c * 9 + tap]; return; }
  idx -= 1728;
  if (idx < 192) {
    float s = bn_g[idx] * rsqrtf(bn_v[idx] + 1e-5f);
    bnsc[idx] = s; bnsh[idx] = bn_b[idx] - bn_m[idx] * s;
  }
}

// ---- LN1 + window partition ----
__global__ __launch_bounds__(256) void ln1_k(
    const float* __restrict__ x, const float* __restrict__ g,
    const float* __restrict__ b, unsigned short* __restrict__ h1)
{
  const int grp = threadIdx.x >> 6, l = threadIdx.x & 63;
  const int m = blockIdx.x * 4 + grp;
  const int w = m / 49, t = m % 49;
  const int bb = w >> 6, win = w & 63;
  const int lpix = ((win >> 3) * 7 + t / 7) * 56 + (win & 7) * 7 + t % 7;
  const float* row = x + ((size_t)bb * LTOT + lpix) * DIMC;
  const bool act = l < 48;
  const int c = l * 4;
  float4 v = make_float4(0.f, 0.f, 0.f, 0.f);
  if (act) v = *(const float4*)(row + c);
  float s = v.x + v.y + v.z + v.w;
  float ss = v.x * v.x + v.y * v.y + v.z * v.z + v.w * v.w;
  #pragma unroll
  for (int off = 1; off < 64; off <<= 1) { s += __shfl_xor(s, off); ss += __shfl_xor(ss, off); }
  float mean = s * (1.f / 192.f);
  float rstd = rsqrtf(ss * (1.f / 192.f) - mean * mean + 1e-5f);
  if (act) {
    float4 gg = *(const float4*)(g + c);
    float4 bv = *(const float4*)(b + c);
    ushort4 o;
    o.x = f2bf((v.x - mean) * rstd * gg.x + bv.x);
    o.y = f2bf((v.y - mean) * rstd * gg.y + bv.y);
    o.z = f2bf((v.z - mean) * rstd * gg.z + bv.z);
    o.w = f2bf((v.w - mean) * rstd * gg.w + bv.w);
    *(ushort4*)(h1 + (size_t)m * DIMC + c) = o;
  }
}

// ---- skinny-K bf16 MFMA GEMM: 128x64 tile, full K=192 staged per chunk ----
// LDS linear [rows][192], T2 swizzle (linear dest + inv-swz source + swz read).
// 4 waves, wave tile 64x32 (4x2 frags). XCD-chunked N-fast block swizzle.
// EPI 0: out bf16 = acc+bias                 (qkv, stride Nreal)
// EPI 1: out bf16 (win-scatter) = x + acc+b  (proj residual -> x1b)
// EPI 2: out bf16 = gelu(acc+bias)           (fc1, stride 384)
// EPI 3: out f32 += acc          (no bias)   (fc2 second half accumulate)
// EPI 4: out f32 = res(bf16) + acc+bias      (fc2 first half)
template<int EPI>
__global__ __launch_bounds__(256) void gemmS_k(
    const unsigned short* __restrict__ Ag, int lda,
    const unsigned short* __restrict__ Bt, int ldb,
    const float* __restrict__ bias, void* __restrict__ outp,
    const void* __restrict__ res, int Nreal, int nN, int K)
{
  __shared__ unsigned short As[128 * 192];
  __shared__ unsigned short Bs[64 * 192];
  const int tid = threadIdx.x;
  const int l = tid & 63, wv = tid >> 6;
  const int u = l >> 4, ll = l & 15;
  const int wm = wv >> 1, wn = wv & 1;

  // bijective XCD-chunk swizzle (gridDim.x always divisible by 8), N-fast
  const int chunk = gridDim.x >> 3;
  const int bid = blockIdx.x;
  const int sid = (bid & 7) * chunk + (bid >> 3);
  const int n_idx = sid % nN, m_idx = sid / nN;
  const int m0 = m_idx * 128, n0 = n_idx * 64;

  f32x4 acc[4][2] = {};
  const int sw = (ll & 7) << 4;

  for (int k0 = 0; k0 < K; k0 += 192) {
    if (k0) __syncthreads();
    // stage A: 128x192 shorts = 49152 B = 12 issues/thread
    #pragma unroll
    for (int i = 0; i < 12; ++i) {
      int ob = i * 4096 + wv * 1024 + l * 16;
      int r = ob / 384, c = ob - r * 384;
      int cs = c ^ ((r & 7) << 4);
      const unsigned short* ga = (const unsigned short*)
          ((const char*)Ag + ((size_t)(m0 + r) * lda + k0) * 2 + cs);
      gload16(ga, &As[ob >> 1]);
    }
    // stage B: 64x192 shorts = 24576 B = 6 issues/thread
    #pragma unroll
    for (int i = 0; i < 6; ++i) {
      int ob = i * 4096 + wv * 1024 + l * 16;
      int r = ob / 384, c = ob - r * 384;
      int cs = c ^ ((r & 7) << 4);
      const unsigned short* ga = (const unsigned short*)
          ((const char*)Bt + ((size_t)(n0 + r) * ldb + k0) * 2 + cs);
      gload16(ga, &Bs[ob >> 1]);
    }
    __syncthreads();
    #pragma unroll
    for (int kk = 0; kk < 6; ++kk) {
      bf16x8 af[4], bfr[2];
      const int cb = (kk * 64 + u * 16) ^ sw;
      #pragma unroll
      for (int mt = 0; mt < 4; ++mt)
        af[mt] = *(const bf16x8*)((const char*)As + (wm * 64 + mt * 16 + ll) * 384 + cb);
      #pragma unroll
      for (int nt = 0; nt < 2; ++nt)
        bfr[nt] = *(const bf16x8*)((const char*)Bs + (wn * 32 + nt * 16 + ll) * 384 + cb);
      #pragma unroll
      for (int mt = 0; mt < 4; ++mt)
        #pragma unroll
        for (int nt = 0; nt < 2; ++nt)
          acc[mt][nt] = __builtin_amdgcn_mfma_f32_16x16x32_bf16(af[mt], bfr[nt], acc[mt][nt], 0, 0, 0);
    }
  }

  #pragma unroll
  for (int mt = 0; mt < 4; ++mt)
  #pragma unroll
  for (int r = 0; r < 4; ++r) {
    const int m = m0 + wm * 64 + mt * 16 + u * 4 + r;
    size_t rowbase = 0;
    if (EPI == 1) {
      int wdw = m / 49, t = m % 49;
      int bb = wdw >> 6, win = wdw & 63;
      int lpix = ((win >> 3) * 7 + t / 7) * 56 + (win & 7) * 7 + t % 7;
      rowbase = ((size_t)bb * LTOT + lpix) * DIMC;
    }
    #pragma unroll
    for (int nt = 0; nt < 2; ++nt) {
      const int n = n0 + wn * 32 + nt * 16 + ll;
      if (n >= Nreal) continue;
      float v = acc[mt][nt][r];
      if (EPI != 3) v += bias[n];
      if (EPI == 0) {
        ((unsigned short*)outp)[(size_t)m * Nreal + n] = f2bf(v);
      } else if (EPI == 1) {
        ((unsigned short*)outp)[rowbase + n] = f2bf(((const float*)res)[rowbase + n] + v);
      } else if (EPI == 2) {
        float gl = 0.5f * v * (1.f + erff(v * 0.70710678118654752f));
        ((unsigned short*)outp)[(size_t)m * 384 + n] = f2bf(gl);
      } else if (EPI == 3) {
        size_t o = (size_t)m * Nreal + n;
        ((float*)outp)[o] += v;
      } else {
        size_t o = (size_t)m * Nreal + n;
        ((float*)outp)[o] = bf2f(((const unsigned short*)res)[o]) + v;
      }
    }
  }
}

// ---- windowed attention: one block per window, loops 6 heads ----
__global__ __launch_bounds__(256) void attn_k(
    const unsigned short* __restrict__ qkv, const float* __restrict__ attn_bias,
    unsigned short* __restrict__ o)
{
  __shared__ unsigned short Qs[64 * 40];
  __shared__ unsigned short Ks[64 * 40];
  __shared__ unsigned short Vt[32 * 72];
  __shared__ unsigned short Ps[64 * 72];
  __shared__ float S[64 * 65];
  __shared__ float bias_s[52];
  const int tid = threadIdx.x;
  const int l = tid & 63, wv = tid >> 6;
  const int u = l >> 4, ll = l & 15;
  const int w = blockIdx.x;
  const f32x4 fz = {0.f, 0.f, 0.f, 0.f};

  for (int i = tid; i < 15 * 40; i += 256) {
    Qs[(49 + i / 40) * 40 + i % 40] = 0;
    Ks[(49 + i / 40) * 40 + i % 40] = 0;
  }
  for (int i = tid; i < 32 * 15; i += 256) Vt[(i / 15) * 72 + 49 + i % 15] = 0;

  for (int h = 0; h < NHEAD; ++h) {
    __syncthreads();
    if (tid < 49) bias_s[tid] = attn_bias[h * 49 + tid];
    #pragma unroll
    for (int it = 0; it < 3; ++it) {
      int idx = tid + it * 256;
      if (idx < 588) {
        int row = idx / 12, g = idx % 12;
        int4 v = *(const int4*)&qkv[((size_t)w * 49 + row) * HQKV + h * 96 + g * 8];
        if (g < 4) *(int4*)&Qs[row * 40 + g * 8] = v;
        else if (g < 8) *(int4*)&Ks[row * 40 + (g - 4) * 8] = v;
        else {
          union { int4 v4; unsigned short us[8]; } uu; uu.v4 = v;
          int d0 = (g - 8) * 8;
          #pragma unroll
          for (int e = 0; e < 8; ++e) Vt[(d0 + e) * 72 + row] = uu.us[e];
        }
      }
    }
    __syncthreads();
    bf16x8 qf = *(const bf16x8*)&Qs[(wv * 16 + ll) * 40 + u * 8];
    f32x4 sc[4];
    #pragma unroll
    for (int nj = 0; nj < 4; ++nj) {
      bf16x8 kf = *(const bf16x8*)&Ks[(nj * 16 + ll) * 40 + u * 8];
      sc[nj] = __builtin_amdgcn_mfma_f32_16x16x32_bf16(qf, kf, fz, 0, 0, 0);
    }
    #pragma unroll
    for (int nj = 0; nj < 4; ++nj)
    #pragma unroll
    for (int r = 0; r < 4; ++r) {
      int i = wv * 16 + u * 4 + r;
      int j = nj * 16 + ll;
      float val = -1e30f;
      if (i < 49 && j < 49) {
        int bi = iabs(i / 7 - j / 7) * 7 + iabs(i % 7 - j % 7);
        val = sc[nj][r] * 0.17677669529663689f + bias_s[bi];
      }
      S[i * 65 + j] = val;
    }
    __syncthreads();
    {
      int row = tid >> 2, t4 = tid & 3;
      float mx = -1e30f;
      #pragma unroll
      for (int jj = 0; jj < 16; ++jj) mx = fmaxf(mx, S[row * 65 + t4 + jj * 4]);
      mx = fmaxf(mx, __shfl_xor(mx, 1));
      mx = fmaxf(mx, __shfl_xor(mx, 2));
      float pv[16], sum = 0.f;
      #pragma unroll
      for (int jj = 0; jj < 16; ++jj) {
        float p = __expf(S[row * 65 + t4 + jj * 4] - mx);
        pv[jj] = p; sum += p;
      }
      sum += __shfl_xor(sum, 1);
      sum += __shfl_xor(sum, 2);
      float inv = 1.f / sum;
      #pragma unroll
      for (int jj = 0; jj < 16; ++jj) Ps[row * 72 + t4 + jj * 4] = f2bf(pv[jj] * inv);
    }
    __syncthreads();
    f32x4 oacc[2]; oacc[0] = fz; oacc[1] = fz;
    #pragma unroll
    for (int kk = 0; kk < 2; ++kk) {
      bf16x8 pf = *(const bf16x8*)&Ps[(wv * 16 + ll) * 72 + kk * 32 + u * 8];
      #pragma unroll
      for (int nt = 0; nt < 2; ++nt) {
        bf16x8 vf = *(const bf16x8*)&Vt[(nt * 16 + ll) * 72 + kk * 32 + u * 8];
        oacc[nt] = __builtin_amdgcn_mfma_f32_16x16x32_bf16(pf, vf, oacc[nt], 0, 0, 0);
      }
    }
    #pragma unroll
    for (int nt = 0; nt < 2; ++nt)
    #pragma unroll
    for (int r = 0; r < 4; ++r) {
      int i = wv * 16 + u * 4 + r;
      if (i < 49) {
        int d = nt * 16 + ll;
        o[((size_t)w * 49 + i) * DIMC + h * 32 + d] = f2bf(oacc[nt][r]);
      }
    }
  }
}

// ---- depthwise 3x3 conv (bf16 in) + BN + LN2, XCD-swizzled ----
__global__ __launch_bounds__(256) void conv_k(
    const unsigned short* __restrict__ x1b, const float* __restrict__ wT,
    const float* __restrict__ bnsc, const float* __restrict__ bnsh,
    const float* __restrict__ g2, const float* __restrict__ b2,
    unsigned short* __restrict__ x2, unsigned short* __restrict__ h2)
{
  const int bid = blockIdx.x;
  const int swz = (bid & 7) * 3136 + (bid >> 3);  // 25088 % 8 == 0: bijective
  const int grp = threadIdx.x >> 6, l = threadIdx.x & 63;
  const int gid = swz * 4 + grp;
  const int b = gid / LTOT, p = gid % LTOT;
  const int i = p / 56, j = p % 56;
  const bool act = l < 48;
  const int c = l * 4;
  float4 acc = make_float4(0.f, 0.f, 0.f, 0.f);
  if (act) {
    #pragma unroll
    for (int di = -1; di <= 1; ++di) {
      int ni = i + di;
      if (ni < 0 || ni >= 56) continue;
      #pragma unroll
      for (int dj = -1; dj <= 1; ++dj) {
        int nj = j + dj;
        if (nj < 0 || nj >= 56) continue;
        ushort4 sv = *(const ushort4*)&x1b[((size_t)b * LTOT + ni * 56 + nj) * DIMC + c];
        float4 wv = *(const float4*)&wT[((di + 1) * 3 + (dj + 1)) * DIMC + c];
        acc.x += bf2f(sv.x) * wv.x; acc.y += bf2f(sv.y) * wv.y;
        acc.z += bf2f(sv.z) * wv.z; acc.w += bf2f(sv.w) * wv.w;
      }
    }
    float4 s4 = *(const float4*)&bnsc[c];
    float4 h4 = *(const float4*)&bnsh[c];
    acc.x = acc.x * s4.x + h4.x; acc.y = acc.y * s4.y + h4.y;
    acc.z = acc.z * s4.z + h4.z; acc.w = acc.w * s4.w + h4.w;
    ushort4 xv;
    xv.x = f2bf(acc.x); xv.y = f2bf(acc.y); xv.z = f2bf(acc.z); xv.w = f2bf(acc.w);
    *(ushort4*)&x2[(size_t)gid * DIMC + c] = xv;
  }
  float s = act ? acc.x + acc.y + acc.z + acc.w : 0.f;
  float ss = act ? acc.x * acc.x + acc.y * acc.y + acc.z * acc.z + acc.w * acc.w : 0.f;
  #pragma unroll
  for (int off = 1; off < 64; off <<= 1) { s += __shfl_xor(s, off); ss += __shfl_xor(ss, off); }
  float mean = s * (1.f / 192.f);
  float rstd = rsqrtf(ss * (1.f / 192.f) - mean * mean + 1e-5f);
  if (act) {
    float4 gg = *(const float4*)&g2[c];
    float4 bb = *(const float4*)&b2[c];
    ushort4 ov;
    ov.x = f2bf((acc.x - mean) * rstd * gg.x + bb.x);
    ov.y = f2bf((acc.y - mean) * rstd * gg.y + bb.y);
    ov.z = f2bf((acc.z - mean) * rstd * gg.z + bb.z);
    ov.w = f2bf((acc.w - mean) * rstd * gg.w + bb.w);
    *(ushort4*)&h2[(size_t)gid * DIMC + c] = ov;
  }
}

extern "C" void kernel_launch(void* const* d_in, const int* in_sizes, int n_in,
                              void* d_out, int out_size, void* d_ws, size_t ws_size,
                              hipStream_t stream) {
  const float* x      = (const float*)d_in[0];
  const float* ln1_g  = (const float*)d_in[1];
  const float* ln1_b  = (const float*)d_in[2];
  const float* qkv_w  = (const float*)d_in[3];
  const float* qkv_b  = (const float*)d_in[4];
  const float* proj_w = (const float*)d_in[5];
  const float* proj_b = (const float*)d_in[6];
  const float* attn_b = (const float*)d_in[7];
  const float* conv_w = (const float*)d_in[8];
  const float* bn_g   = (const float*)d_in[9];
  const float* bn_b   = (const float*)d_in[10];
  const float* bn_m   = (const float*)d_in[11];
  const float* bn_v   = (const float*)d_in[12];
  const float* ln2_g  = (const float*)d_in[13];
  const float* ln2_b  = (const float*)d_in[14];
  const float* fc1_w  = (const float*)d_in[15];
  const float* fc1_b  = (const float*)d_in[16];
  const float* fc2_w  = (const float*)d_in[17];
  const float* fc2_b  = (const float*)d_in[18];
  float* out = (float*)d_out;

  // workspace layout, peak 155,189,248 B (same as passing rounds):
  //  WREG [0,1MiB): qkvT(640x192) projT(256x192) fc1T(768x192) fc2T(256x768) convT bnsc bnsh
  //  A [1MiB, +115,605,504): qkv bf16 [M][576] -> x1b@A (38.5MB) -> h3@A (77MB); h2@A+77,070,336
  //  B [A_end, +38,535,168): h1 -> owin -> x2
  const size_t AOFF = 1048576, BOFF = AOFF + 115605504;
  const size_t NEEDED = BOFF + 38535168;
  if (ws_size < NEEDED) return;

  char* ws = (char*)d_ws;
  unsigned short* qkvT  = (unsigned short*)(ws);
  unsigned short* projT = (unsigned short*)(ws + 245760);
  unsigned short* fc1T  = (unsigned short*)(ws + 344064);
  unsigned short* fc2T  = (unsigned short*)(ws + 638976);
  float*          convT = (float*)(ws + 1032192);
  float*          bnsc  = (float*)(ws + 1039104);
  float*          bnsh  = (float*)(ws + 1039872);

  unsigned short* qkv  = (unsigned short*)(ws + AOFF);
  unsigned short* x1b  = (unsigned short*)(ws + AOFF);
  unsigned short* h3   = (unsigned short*)(ws + AOFF);
  unsigned short* h2   = (unsigned short*)(ws + AOFF + 77070336);
  unsigned short* h1   = (unsigned short*)(ws + BOFF);
  unsigned short* owin = (unsigned short*)(ws + BOFF);
  unsigned short* x2   = (unsigned short*)(ws + BOFF);

  prep_k<<<2024, 256, 0, stream>>>(qkv_w, proj_w, fc1_w, fc2_w, conv_w,
                                   bn_g, bn_b, bn_m, bn_v,
                                   qkvT, projT, fc1T, fc2T, convT, bnsc, bnsh);
  ln1_k<<<25088, 256, 0, stream>>>(x, ln1_g, ln1_b, h1);
  // qkv: M=100352 K=192 N=576 -> 784 * 9 blocks
  gemmS_k<0><<<784 * 9, 256, 0, stream>>>(h1, 192, qkvT, 192, qkv_b, qkv, nullptr, 576, 9, 192);
  attn_k<<<2048, 256, 0, stream>>>(qkv, attn_b, owin);
  // proj: N=192 -> 784 * 3
  gemmS_k<1><<<784 * 3, 256, 0, stream>>>(owin, 192, projT, 192, proj_b, x1b, x, 192, 3, 192);
  conv_k<<<25088, 256, 0, stream>>>(x1b, convT, bnsc, bnsh, ln2_g, ln2_b, x2, h2);
  // MLP: hidden split 2x384; fc1 halves N=384 (784*6), fc2 halves K=384 (784*3)
  gemmS_k<2><<<784 * 6, 256, 0, stream>>>(h2, 192, fc1T, 192, fc1_b, h3, nullptr, 384, 6, 192);
  gemmS_k<4><<<784 * 3, 256, 0, stream>>>(h3, 384, fc2T, 768, fc2_b, out, x2, 192, 3, 384);
  gemmS_k<2><<<784 * 6, 256, 0, stream>>>(h2, 192, fc1T + 384 * 192, 192, fc1_b + 384, h3, nullptr, 384, 6, 192);
  gemmS_k<3><<<784 * 3, 256, 0, stream>>>(h3, 384, fc2T + 384, 768, nullptr, out, nullptr, 192, 3, 384);
}

// Round 7
// 451.284 us; speedup vs baseline: 1.7060x; 1.5121x over previous
//
#include <hip/hip_runtime.h>
#include <hip/hip_bf16.h>

#define DIMC 192
#define LTOT 3136

using bf16x8 = __attribute__((ext_vector_type(8))) short;
using f32x4  = __attribute__((ext_vector_type(4))) float;

static __device__ __forceinline__ unsigned short f2bf(float f) {
  unsigned u = __builtin_bit_cast(unsigned, f);
  u = (u + 0x7FFFu + ((u >> 16) & 1u)) >> 16;
  return (unsigned short)u;
}
static __device__ __forceinline__ float bf2f(unsigned short u) {
  unsigned v = ((unsigned)u) << 16;
  return __builtin_bit_cast(float, v);
}
static __device__ __forceinline__ int iabs(int a) { return a < 0 ? -a : a; }

static __device__ __forceinline__ void gload16(const unsigned short* g, unsigned short* lds) {
  __builtin_amdgcn_global_load_lds(
      (const __attribute__((address_space(1))) void*)g,
      (__attribute__((address_space(3))) void*)lds, 16, 0, 0);
}

// ---- prep: weights -> bf16 W^T [Npad][K]; conv w; BN fold ----
__global__ __launch_bounds__(256) void prep_k(
    const float* __restrict__ qkv_w, const float* __restrict__ proj_w,
    const float* __restrict__ fc1_w, const float* __restrict__ fc2_w,
    const float* __restrict__ conv_w,
    const float* __restrict__ bn_g, const float* __restrict__ bn_b,
    const float* __restrict__ bn_m, const float* __restrict__ bn_v,
    unsigned short* __restrict__ qkvT, unsigned short* __restrict__ projT,
    unsigned short* __restrict__ fc1T, unsigned short* __restrict__ fc2T,
    float* __restrict__ convT, float* __restrict__ bnsc, float* __restrict__ bnsh)
{
  int idx = blockIdx.x * 256 + threadIdx.x;
  if (idx < 122880) { int n = idx / 192, k = idx % 192;
    qkvT[idx] = (n < 576) ? f2bf(qkv_w[k * 576 + n]) : 0; return; }
  idx -= 122880;
  if (idx < 49152)  { int n = idx / 192, k = idx % 192;
    projT[idx] = (n < 192) ? f2bf(proj_w[k * 192 + n]) : 0; return; }
  idx -= 49152;
  if (idx < 147456) { int n = idx / 192, k = idx % 192;
    fc1T[idx] = f2bf(fc1_w[k * 768 + n]); return; }
  idx -= 147456;
  if (idx < 196608) { int n = idx / 768, k = idx % 768;
    fc2T[idx] = (n < 192) ? f2bf(fc2_w[k * 192 + n]) : 0; return; }
  idx -= 196608;
  if (idx < 1728)   { int tap = idx / 192, c = idx % 192; convT[idx] = conv_w[c * 9 + tap]; return; }
  idx -= 1728;
  if (idx < 192) {
    float s = bn_g[idx] * rsqrtf(bn_v[idx] + 1e-5f);
    bnsc[idx] = s; bnsh[idx] = bn_b[idx] - bn_m[idx] * s;
  }
}

// ---- fused attention block: LN1 + qkv + attn + proj + residual, 1 window/block ----
__global__ __launch_bounds__(512) void fattn_k(
    const float* __restrict__ x, const float* __restrict__ ln_g, const float* __restrict__ ln_b,
    const unsigned short* __restrict__ qkvT, const float* __restrict__ qkv_b,
    const unsigned short* __restrict__ projT, const float* __restrict__ proj_b,
    const float* __restrict__ attn_bias, unsigned short* __restrict__ x1b)
{
  __shared__ unsigned short xr[9408];    // raw x bf16 (residual)
  __shared__ unsigned short As[12288];   // LN'd A [64][192] XOR-swizzled
  __shared__ unsigned short Ws[18432];   // W_qkv head slice [96][192] swizzled
  __shared__ unsigned short Wp[7680];    // W_proj head slice [192][40]
  __shared__ unsigned short Qs[2560];    // Q [64][40] (reused as o after QK^T)
  __shared__ unsigned short Ks[2560];    // K [64][40]
  __shared__ unsigned short Vt[2304];    // V^T [32][72]
  __shared__ unsigned short Ps[4608];    // probs [64][72]
  __shared__ float S[4160];              // scores [64][65]
  __shared__ float bias_s[52];

  const int tid = threadIdx.x;
  const int l = tid & 63, wv = tid >> 6;
  const int u = l >> 4, ll = l & 15;
  const int w = blockIdx.x, b = w >> 6, win = w & 63;
  const f32x4 fz = {0.f, 0.f, 0.f, 0.f};

  // ---- LN1 + stash residual ----
  for (int t = wv; t < 49; t += 8) {
    int lpix = ((win >> 3) * 7 + t / 7) * 56 + (win & 7) * 7 + t % 7;
    const float* row = x + ((size_t)b * LTOT + lpix) * DIMC;
    bool act = l < 48;
    int c = l * 4;
    float4 v = make_float4(0.f, 0.f, 0.f, 0.f);
    if (act) v = *(const float4*)(row + c);
    float s = v.x + v.y + v.z + v.w;
    float ss = v.x * v.x + v.y * v.y + v.z * v.z + v.w * v.w;
    #pragma unroll
    for (int off = 1; off < 64; off <<= 1) { s += __shfl_xor(s, off); ss += __shfl_xor(ss, off); }
    float mean = s * (1.f / 192.f);
    float rstd = rsqrtf(ss * (1.f / 192.f) - mean * mean + 1e-5f);
    if (act) {
      ushort4 xb;
      xb.x = f2bf(v.x); xb.y = f2bf(v.y); xb.z = f2bf(v.z); xb.w = f2bf(v.w);
      *(ushort4*)&xr[t * 192 + c] = xb;
      float4 gg = *(const float4*)(ln_g + c);
      float4 bb = *(const float4*)(ln_b + c);
      ushort4 o4;
      o4.x = f2bf((v.x - mean) * rstd * gg.x + bb.x);
      o4.y = f2bf((v.y - mean) * rstd * gg.y + bb.y);
      o4.z = f2bf((v.z - mean) * rstd * gg.z + bb.z);
      o4.w = f2bf((v.w - mean) * rstd * gg.w + bb.w);
      int abyte = t * 384 + ((l * 8) ^ ((t & 7) << 4));
      *(ushort4*)((char*)As + abyte) = o4;
    }
  }
  // zero-pad A rows 49..63 (swizzle-bijective within row)
  {
    ushort4 z4; z4.x = z4.y = z4.z = z4.w = 0;
    for (int i = tid; i < 720; i += 512) {
      int r = 49 + i / 48, cb = (i % 48) * 8;
      *(ushort4*)((char*)As + r * 384 + (cb ^ ((r & 7) << 4))) = z4;
    }
  }

  f32x4 pacc[2][3] = {};
  const int np = wv >> 1, mh = wv & 1;

  for (int h = 0; h < 6; ++h) {
    __syncthreads();  // protect Ws/Wp/bias_s vs previous head readers
    // stage W_qkv slice [96][192] swizzled via gload_lds
    const char* Wg = (const char*)(qkvT + (size_t)h * 96 * 192);
    #pragma unroll
    for (int i = 0; i < 5; ++i) {
      int ob = i * 8192 + tid * 16;
      if (ob < 36864) {
        int r = ob / 384, c = ob % 384;
        int cs = c ^ ((r & 7) << 4);
        gload16((const unsigned short*)(Wg + r * 384 + cs), &Ws[ob >> 1]);
      }
    }
    // stage W_proj slice [192 n][32 k] -> [192][40]
    #pragma unroll
    for (int i = 0; i < 2; ++i) {
      int unit = i * 512 + tid;
      if (unit < 768) {
        int r = unit >> 2, q = unit & 3;
        int4 vv = *(const int4*)&projT[(size_t)r * 192 + h * 32 + q * 8];
        *(int4*)&Wp[r * 40 + q * 8] = vv;
      }
    }
    if (tid < 49) bias_s[tid] = attn_bias[h * 49 + tid];
    __syncthreads();

    // ---- Q (waves 0-3) or K (waves 4-7), 16-row strip each ----
    {
      const int mstrip = (wv < 4) ? wv : wv - 4;
      const int woff = (wv < 4) ? 0 : 32;
      f32x4 qk[2] = {fz, fz};
      #pragma unroll
      for (int kk = 0; kk < 6; ++kk) {
        int cb = (kk * 64 + u * 16) ^ ((ll & 7) << 4);
        bf16x8 af = *(const bf16x8*)((const char*)As + (mstrip * 16 + ll) * 384 + cb);
        #pragma unroll
        for (int nt = 0; nt < 2; ++nt) {
          bf16x8 bfr = *(const bf16x8*)((const char*)Ws + (woff + nt * 16 + ll) * 384 + cb);
          qk[nt] = __builtin_amdgcn_mfma_f32_16x16x32_bf16(af, bfr, qk[nt], 0, 0, 0);
        }
      }
      unsigned short* dst = (wv < 4) ? Qs : Ks;
      #pragma unroll
      for (int nt = 0; nt < 2; ++nt)
        #pragma unroll
        for (int r = 0; r < 4; ++r)
          dst[(mstrip * 16 + u * 4 + r) * 40 + nt * 16 + ll] =
              f2bf(qk[nt][r] + qkv_b[h * 96 + woff + nt * 16 + ll]);
    }
    // ---- V^T subtile per wave: D[d][t] = Wv @ A^T ----
    {
      const int ntv = wv & 3, mtv = wv >> 2;
      f32x4 vacc = fz;
      #pragma unroll
      for (int kk = 0; kk < 6; ++kk) {
        int cb = (kk * 64 + u * 16) ^ ((ll & 7) << 4);
        bf16x8 wa = *(const bf16x8*)((const char*)Ws + (64 + mtv * 16 + ll) * 384 + cb);
        bf16x8 ab = *(const bf16x8*)((const char*)As + (ntv * 16 + ll) * 384 + cb);
        vacc = __builtin_amdgcn_mfma_f32_16x16x32_bf16(wa, ab, vacc, 0, 0, 0);
      }
      #pragma unroll
      for (int r = 0; r < 4; ++r) {
        int d = mtv * 16 + u * 4 + r;
        Vt[d * 72 + ntv * 16 + ll] = f2bf(vacc[r] + qkv_b[h * 96 + 64 + d]);
      }
    }
    __syncthreads();

    // ---- QK^T (K-dim 32 = one MFMA) ----
    {
      const int s2 = wv >> 1, njp = wv & 1;
      bf16x8 qf = *(const bf16x8*)&Qs[(s2 * 16 + ll) * 40 + u * 8];
      f32x4 sc[2];
      #pragma unroll
      for (int jp = 0; jp < 2; ++jp) {
        int nj = njp * 2 + jp;
        bf16x8 kf = *(const bf16x8*)&Ks[(nj * 16 + ll) * 40 + u * 8];
        sc[jp] = __builtin_amdgcn_mfma_f32_16x16x32_bf16(qf, kf, fz, 0, 0, 0);
      }
      #pragma unroll
      for (int jp = 0; jp < 2; ++jp)
        #pragma unroll
        for (int r = 0; r < 4; ++r) {
          int i = s2 * 16 + u * 4 + r;
          int j = (njp * 2 + jp) * 16 + ll;
          float val = -1e30f;
          if (i < 49 && j < 49)
            val = sc[jp][r] * 0.17677669529663689f +
                  bias_s[iabs(i / 7 - j / 7) * 7 + iabs(i % 7 - j % 7)];
          S[i * 65 + j] = val;
        }
    }
    __syncthreads();

    // ---- softmax: 8 lanes per row ----
    {
      int row = tid >> 3, t8 = tid & 7;
      float mx = -1e30f, pv[8];
      #pragma unroll
      for (int jj = 0; jj < 8; ++jj) mx = fmaxf(mx, S[row * 65 + t8 + jj * 8]);
      mx = fmaxf(mx, __shfl_xor(mx, 1));
      mx = fmaxf(mx, __shfl_xor(mx, 2));
      mx = fmaxf(mx, __shfl_xor(mx, 4));
      float sum = 0.f;
      #pragma unroll
      for (int jj = 0; jj < 8; ++jj) {
        float p = __expf(S[row * 65 + t8 + jj * 8] - mx);
        pv[jj] = p; sum += p;
      }
      sum += __shfl_xor(sum, 1);
      sum += __shfl_xor(sum, 2);
      sum += __shfl_xor(sum, 4);
      float inv = 1.f / sum;
      #pragma unroll
      for (int jj = 0; jj < 8; ++jj) Ps[row * 72 + t8 + jj * 8] = f2bf(pv[jj] * inv);
    }
    __syncthreads();

    // ---- PV: o[q][d], stage into Qs (dead) ----
    {
      const int s = wv >> 1, nt = wv & 1;
      f32x4 oa = fz;
      #pragma unroll
      for (int kk = 0; kk < 2; ++kk) {
        bf16x8 pf = *(const bf16x8*)&Ps[(s * 16 + ll) * 72 + kk * 32 + u * 8];
        bf16x8 vf = *(const bf16x8*)&Vt[(nt * 16 + ll) * 72 + kk * 32 + u * 8];
        oa = __builtin_amdgcn_mfma_f32_16x16x32_bf16(pf, vf, oa, 0, 0, 0);
      }
      #pragma unroll
      for (int r = 0; r < 4; ++r)
        Qs[(s * 16 + u * 4 + r) * 40 + nt * 16 + ll] = f2bf(oa[r]);
    }
    __syncthreads();

    // ---- proj accumulate (K=32 per head) ----
    {
      bf16x8 af[2], bfr[3];
      #pragma unroll
      for (int mtl = 0; mtl < 2; ++mtl)
        af[mtl] = *(const bf16x8*)&Qs[((mh * 2 + mtl) * 16 + ll) * 40 + u * 8];
      #pragma unroll
      for (int nf = 0; nf < 3; ++nf)
        bfr[nf] = *(const bf16x8*)&Wp[(np * 48 + nf * 16 + ll) * 40 + u * 8];
      #pragma unroll
      for (int mtl = 0; mtl < 2; ++mtl)
        #pragma unroll
        for (int nf = 0; nf < 3; ++nf)
          pacc[mtl][nf] = __builtin_amdgcn_mfma_f32_16x16x32_bf16(af[mtl], bfr[nf], pacc[mtl][nf], 0, 0, 0);
    }
  }

  // ---- epilogue: + proj_b + residual -> x1b (window scatter) ----
  #pragma unroll
  for (int mtl = 0; mtl < 2; ++mtl)
  #pragma unroll
  for (int r = 0; r < 4; ++r) {
    int m = (mh * 2 + mtl) * 16 + u * 4 + r;
    if (m < 49) {
      int lpix = ((win >> 3) * 7 + m / 7) * 56 + (win & 7) * 7 + m % 7;
      size_t base = ((size_t)b * LTOT + lpix) * DIMC;
      #pragma unroll
      for (int nf = 0; nf < 3; ++nf) {
        int n = np * 48 + nf * 16 + ll;
        float val = pacc[mtl][nf][r] + proj_b[n] + bf2f(xr[m * 192 + n]);
        x1b[base + n] = f2bf(val);
      }
    }
  }
}

// ---- fused MLP: fc1 + gelu + fc2 + residual, hidden on the fly ----
__global__ __launch_bounds__(256) void fmlp_k(
    const unsigned short* __restrict__ h2, const unsigned short* __restrict__ fc1T,
    const float* __restrict__ fc1_b, const unsigned short* __restrict__ fc2T,
    const float* __restrict__ fc2_b, const unsigned short* __restrict__ x2,
    float* __restrict__ out)
{
  __shared__ unsigned short As[12288];  // A [64][192] swizzled
  __shared__ unsigned short W1[12288];  // fc1 chunk [64][192] swizzled
  __shared__ unsigned short W2[12288];  // fc2 chunk [192][64] swizzled
  __shared__ unsigned short P[4096];    // gelu(fc1) [64][64] swizzled
  const int tid = threadIdx.x;
  const int l = tid & 63, wv = tid >> 6;
  const int u = l >> 4, ll = l & 15;
  const int m0 = blockIdx.x * 64;
  f32x4 acc[4][3] = {};

  #pragma unroll
  for (int i = 0; i < 6; ++i) {
    int ob = i * 4096 + tid * 16;
    int r = ob / 384, c = ob % 384;
    int cs = c ^ ((r & 7) << 4);
    gload16((const unsigned short*)((const char*)h2 + (size_t)(m0 + r) * 384 + cs), &As[ob >> 1]);
  }
  for (int c = 0; c < 12; ++c) {
    const char* W1g = (const char*)(fc1T + (size_t)c * 64 * 192);
    #pragma unroll
    for (int i = 0; i < 6; ++i) {
      int ob = i * 4096 + tid * 16;
      int r = ob / 384, cc = ob % 384;
      int cs = cc ^ ((r & 7) << 4);
      gload16((const unsigned short*)(W1g + r * 384 + cs), &W1[ob >> 1]);
    }
    // W2 chunk: 192 rows x 64 cols = 1536 int4 units -> 6 iterations
    #pragma unroll
    for (int i = 0; i < 6; ++i) {
      int unit = i * 256 + tid;
      int r = unit >> 3, q = unit & 7;
      int4 vv = *(const int4*)&fc2T[(size_t)r * 768 + c * 64 + q * 8];
      *(int4*)((char*)W2 + r * 128 + ((q * 16) ^ ((r & 7) << 4))) = vv;
    }
    __syncthreads();
    // fc1: wave m-strip, N=64 chunk
    {
      f32x4 p1[4] = {};
      #pragma unroll
      for (int kk = 0; kk < 6; ++kk) {
        int cb = (kk * 64 + u * 16) ^ ((ll & 7) << 4);
        bf16x8 af = *(const bf16x8*)((const char*)As + (wv * 16 + ll) * 384 + cb);
        #pragma unroll
        for (int nf = 0; nf < 4; ++nf) {
          bf16x8 bfr = *(const bf16x8*)((const char*)W1 + (nf * 16 + ll) * 384 + cb);
          p1[nf] = __builtin_amdgcn_mfma_f32_16x16x32_bf16(af, bfr, p1[nf], 0, 0, 0);
        }
      }
      #pragma unroll
      for (int nf = 0; nf < 4; ++nf)
      #pragma unroll
      for (int r = 0; r < 4; ++r) {
        int mrow = wv * 16 + u * 4 + r;
        int n = nf * 16 + ll;
        float v = p1[nf][r] + fc1_b[c * 64 + n];
        float gl = 0.5f * v * (1.f + erff(v * 0.70710678118654752f));
        *(unsigned short*)((char*)P + mrow * 128 + ((n * 2) ^ ((mrow & 7) << 4))) = f2bf(gl);
      }
    }
    __syncthreads();
    // fc2: wave n-strip 48, K=64 chunk accumulate
    {
      #pragma unroll
      for (int kk = 0; kk < 2; ++kk) {
        int cb = kk * 64 + u * 16;
        bf16x8 bfr[3];
        #pragma unroll
        for (int nf = 0; nf < 3; ++nf)
          bfr[nf] = *(const bf16x8*)((const char*)W2 + (wv * 48 + nf * 16 + ll) * 128 + (cb ^ ((ll & 7) << 4)));
        #pragma unroll
        for (int mt = 0; mt < 4; ++mt) {
          bf16x8 af2 = *(const bf16x8*)((const char*)P + (mt * 16 + ll) * 128 + (cb ^ ((ll & 7) << 4)));
          #pragma unroll
          for (int nf = 0; nf < 3; ++nf)
            acc[mt][nf] = __builtin_amdgcn_mfma_f32_16x16x32_bf16(af2, bfr[nf], acc[mt][nf], 0, 0, 0);
        }
      }
    }
    __syncthreads();
  }
  #pragma unroll
  for (int mt = 0; mt < 4; ++mt)
  #pragma unroll
  for (int r = 0; r < 4; ++r) {
    int m = m0 + mt * 16 + u * 4 + r;
    #pragma unroll
    for (int nf = 0; nf < 3; ++nf) {
      int n = wv * 48 + nf * 16 + ll;
      size_t o = (size_t)m * 192 + n;
      out[o] = acc[mt][nf][r] + fc2_b[n] + bf2f(x2[o]);
    }
  }
}

// ---- depthwise 3x3 conv (bf16 in) + BN + LN2, XCD-swizzled ----
__global__ __launch_bounds__(256) void conv_k(
    const unsigned short* __restrict__ x1b, const float* __restrict__ wT,
    const float* __restrict__ bnsc, const float* __restrict__ bnsh,
    const float* __restrict__ g2, const float* __restrict__ b2,
    unsigned short* __restrict__ x2, unsigned short* __restrict__ h2)
{
  const int bid = blockIdx.x;
  const int swz = (bid & 7) * 3136 + (bid >> 3);
  const int grp = threadIdx.x >> 6, l = threadIdx.x & 63;
  const int gid = swz * 4 + grp;
  const int b = gid / LTOT, p = gid % LTOT;
  const int i = p / 56, j = p % 56;
  const bool act = l < 48;
  const int c = l * 4;
  float4 acc = make_float4(0.f, 0.f, 0.f, 0.f);
  if (act) {
    #pragma unroll
    for (int di = -1; di <= 1; ++di) {
      int ni = i + di;
      if (ni < 0 || ni >= 56) continue;
      #pragma unroll
      for (int dj = -1; dj <= 1; ++dj) {
        int nj = j + dj;
        if (nj < 0 || nj >= 56) continue;
        ushort4 sv = *(const ushort4*)&x1b[((size_t)b * LTOT + ni * 56 + nj) * DIMC + c];
        float4 wv = *(const float4*)&wT[((di + 1) * 3 + (dj + 1)) * DIMC + c];
        acc.x += bf2f(sv.x) * wv.x; acc.y += bf2f(sv.y) * wv.y;
        acc.z += bf2f(sv.z) * wv.z; acc.w += bf2f(sv.w) * wv.w;
      }
    }
    float4 s4 = *(const float4*)&bnsc[c];
    float4 h4 = *(const float4*)&bnsh[c];
    acc.x = acc.x * s4.x + h4.x; acc.y = acc.y * s4.y + h4.y;
    acc.z = acc.z * s4.z + h4.z; acc.w = acc.w * s4.w + h4.w;
    ushort4 xv;
    xv.x = f2bf(acc.x); xv.y = f2bf(acc.y); xv.z = f2bf(acc.z); xv.w = f2bf(acc.w);
    *(ushort4*)&x2[(size_t)gid * DIMC + c] = xv;
  }
  float s = act ? acc.x + acc.y + acc.z + acc.w : 0.f;
  float ss = act ? acc.x * acc.x + acc.y * acc.y + acc.z * acc.z + acc.w * acc.w : 0.f;
  #pragma unroll
  for (int off = 1; off < 64; off <<= 1) { s += __shfl_xor(s, off); ss += __shfl_xor(ss, off); }
  float mean = s * (1.f / 192.f);
  float rstd = rsqrtf(ss * (1.f / 192.f) - mean * mean + 1e-5f);
  if (act) {
    float4 gg = *(const float4*)&g2[c];
    float4 bb = *(const float4*)&b2[c];
    ushort4 ov;
    ov.x = f2bf((acc.x - mean) * rstd * gg.x + bb.x);
    ov.y = f2bf((acc.y - mean) * rstd * gg.y + bb.y);
    ov.z = f2bf((acc.z - mean) * rstd * gg.z + bb.z);
    ov.w = f2bf((acc.w - mean) * rstd * gg.w + bb.w);
    *(ushort4*)&h2[(size_t)gid * DIMC + c] = ov;
  }
}

extern "C" void kernel_launch(void* const* d_in, const int* in_sizes, int n_in,
                              void* d_out, int out_size, void* d_ws, size_t ws_size,
                              hipStream_t stream) {
  const float* x      = (const float*)d_in[0];
  const float* ln1_g  = (const float*)d_in[1];
  const float* ln1_b  = (const float*)d_in[2];
  const float* qkv_w  = (const float*)d_in[3];
  const float* qkv_b  = (const float*)d_in[4];
  const float* proj_w = (const float*)d_in[5];
  const float* proj_b = (const float*)d_in[6];
  const float* attn_b = (const float*)d_in[7];
  const float* conv_w = (const float*)d_in[8];
  const float* bn_g   = (const float*)d_in[9];
  const float* bn_b   = (const float*)d_in[10];
  const float* bn_m   = (const float*)d_in[11];
  const float* bn_v   = (const float*)d_in[12];
  const float* ln2_g  = (const float*)d_in[13];
  const float* ln2_b  = (const float*)d_in[14];
  const float* fc1_w  = (const float*)d_in[15];
  const float* fc1_b  = (const float*)d_in[16];
  const float* fc2_w  = (const float*)d_in[17];
  const float* fc2_b  = (const float*)d_in[18];
  float* out = (float*)d_out;

  // workspace: WREG [0,1MiB) weights; x1b @1MiB (38.5MB); h2; x2. ~111 MiB total.
  const size_t AOFF = 1048576;
  const size_t NEEDED = AOFF + 3 * 38535168;
  if (ws_size < NEEDED) return;

  char* ws = (char*)d_ws;
  unsigned short* qkvT  = (unsigned short*)(ws);
  unsigned short* projT = (unsigned short*)(ws + 245760);
  unsigned short* fc1T  = (unsigned short*)(ws + 344064);
  unsigned short* fc2T  = (unsigned short*)(ws + 638976);
  float*          convT = (float*)(ws + 1032192);
  float*          bnsc  = (float*)(ws + 1039104);
  float*          bnsh  = (float*)(ws + 1039872);

  unsigned short* x1b = (unsigned short*)(ws + AOFF);
  unsigned short* h2  = (unsigned short*)(ws + AOFF + 38535168);
  unsigned short* x2  = (unsigned short*)(ws + AOFF + 2 * 38535168);

  prep_k<<<2024, 256, 0, stream>>>(qkv_w, proj_w, fc1_w, fc2_w, conv_w,
                                   bn_g, bn_b, bn_m, bn_v,
                                   qkvT, projT, fc1T, fc2T, convT, bnsc, bnsh);
  fattn_k<<<2048, 512, 0, stream>>>(x, ln1_g, ln1_b, qkvT, qkv_b, projT, proj_b, attn_b, x1b);
  conv_k<<<25088, 256, 0, stream>>>(x1b, convT, bnsc, bnsh, ln2_g, ln2_b, x2, h2);
  fmlp_k<<<1568, 256, 0, stream>>>(h2, fc1T, fc1_b, fc2T, fc2_b, x2, out);
}